// Round 1
// baseline (146.902 us; speedup 1.0000x reference)
//
#include <hip/hip_runtime.h>
#include <math.h>

#define S_DIM 8
#define N_RES 256
#define MSA_DIM 256
#define PAIR_DIM 128
#define D_DIM 32
#define H_DIM 8
#define M_ROWS (S_DIM * N_RES)      // 2048
#define QKV_N (3 * H_DIM * D_DIM)   // 768
#define HD (H_DIM * D_DIM)          // 256
#define XW_N 1024                   // qkv(768) + gate(256)
#define LOG2E 1.4426950408889634f

typedef __attribute__((ext_vector_type(8))) short short8;
typedef __attribute__((ext_vector_type(4))) float floatx4;

// ---- wave64 sum via DPP; total lands in lane 63
#define DPP_ADD(x, ctrl, rmask)                                                \
    x += __int_as_float(__builtin_amdgcn_update_dpp(                           \
        0, __float_as_int(x), (ctrl), (rmask), 0xf, true))

__device__ __forceinline__ float wave_sum63(float x) {
    DPP_ADD(x, 0x111, 0xf);
    DPP_ADD(x, 0x112, 0xf);
    DPP_ADD(x, 0x114, 0xf);
    DPP_ADD(x, 0x118, 0xf);
    DPP_ADD(x, 0x142, 0xa);
    DPP_ADD(x, 0x143, 0xc);
    return x;
}

__device__ __forceinline__ float quad_sum(float x) {
    x += __int_as_float(__builtin_amdgcn_update_dpp(
        0, __float_as_int(x), 0xB1, 0xf, 0xf, true));
    x += __int_as_float(__builtin_amdgcn_update_dpp(
        0, __float_as_int(x), 0x4E, 0xf, 0xf, true));
    return x;
}

__device__ __forceinline__ unsigned short bf16rn(float v) {
    unsigned u = __float_as_uint(v);
    return (unsigned short)((u + 0x7FFF + ((u >> 16) & 1)) >> 16);
}

// =========== Kernel 1 "prep": LN(msa) + wconv(W, w_out) ====================
// blocks [0,2048):    LayerNorm msa -> xhi/xlo bf16
// blocks [2048,2176): split+transpose w_qkv|w_g -> whiT/wloT [1024 n][256 k]
// blocks [2176,2208): split+transpose+perm w_out -> wouthiT/woutloT [256][256]
__global__ __launch_bounds__(256) void prep_kernel(
    const float* __restrict__ w_qkv, const float* __restrict__ w_g,
    unsigned short* __restrict__ whiT, unsigned short* __restrict__ wloT,
    const float* __restrict__ w_out,
    unsigned short* __restrict__ wouthiT, unsigned short* __restrict__ woutloT,
    const float* __restrict__ msa, const float* __restrict__ lnw,
    const float* __restrict__ lnb, unsigned short* __restrict__ xhi,
    unsigned short* __restrict__ xlo)
{
    __shared__ float shm[8];
    int bx = blockIdx.x;
    int t = threadIdx.x;

    if (bx < 2048) {
        // ---------------- LayerNorm of msa ----------------
        int row = bx;
        float v = msa[row * MSA_DIM + t];
        float s1 = wave_sum63(v);
        float s2 = wave_sum63(v * v);
        float* r1 = shm;
        float* r2 = shm + 4;
        int wave = t >> 6, lane = t & 63;
        if (lane == 63) { r1[wave] = s1; r2[wave] = s2; }
        __syncthreads();
        float S1 = r1[0] + r1[1] + r1[2] + r1[3];
        float S2 = r2[0] + r2[1] + r2[2] + r2[3];
        float mu = S1 * (1.0f / 256.0f);
        float var = S2 * (1.0f / 256.0f) - mu * mu;
        float rs = rsqrtf(var + 1e-5f);
        float y = (v - mu) * rs * lnw[t] + lnb[t];
        unsigned short h = bf16rn(y);
        xhi[row * 256 + t] = h;
        xlo[row * 256 + t] = bf16rn(y - __uint_as_float((unsigned)h << 16));
    } else if (bx < 2176) {
        // ---------------- wconv for W = [w_qkv | w_g] ----------------
        int id = (bx - 2048) * 256 + t;       // 32768
        int n = id >> 5, oct = id & 31, k0 = oct * 8;
        const float* src;
        int stride;
        if (n < QKV_N) { src = w_qkv + n; stride = QKV_N; }
        else           { src = w_g + (n - QKV_N); stride = HD; }
        unsigned short h8[8], l8[8];
#pragma unroll
        for (int j = 0; j < 8; j++) {
            float v = src[(size_t)(k0 + j) * stride];
            unsigned short h = bf16rn(v);
            h8[j] = h;
            l8[j] = bf16rn(v - __uint_as_float((unsigned)h << 16));
        }
        *(short8*)&whiT[n * 256 + k0] = *(short8*)h8;
        *(short8*)&wloT[n * 256 + k0] = *(short8*)l8;
    } else {
        // ------- wconv for w_out (ao-layout row perm) -------
        int id = (bx - 2176) * 256 + t;       // 8192
        int n = id >> 5, oct = id & 31, k0 = oct * 8;
        unsigned short h8[8], l8[8];
#pragma unroll
        for (int j = 0; j < 8; j++) {
            int k = k0 + j;
            int wrow = (k & 31) * 8 + (k >> 5);
            float v = w_out[(size_t)wrow * 256 + n];
            unsigned short h = bf16rn(v);
            h8[j] = h;
            l8[j] = bf16rn(v - __uint_as_float((unsigned)h << 16));
        }
        *(short8*)&wouthiT[n * 256 + k0] = *(short8*)h8;
        *(short8*)&woutloT[n * 256 + k0] = *(short8*)l8;
    }
}

// ====== Kernel 2 "mid": pair_bias (1024 blocks) || xw GEMM (512 blocks) ====
// Roles interleaved (bx%3==2 -> GEMM) so HBM-streaming pair blocks and
// latency-bound MFMA blocks co-reside on each CU.
// GEMM: 64x64 tiles, grid-equivalent (16 n)x(32 m) = 512 blocks -> 2
// blocks/CU (2 waves/SIMD) instead of the old 256-block (1 wave/SIMD) config.
__global__ __launch_bounds__(256) void mid_kernel(
    const float* __restrict__ pair, const float* __restrict__ lw,
    const float* __restrict__ lb, const float* __restrict__ wb,
    float* __restrict__ b2,
    const unsigned short* __restrict__ xhi, const unsigned short* __restrict__ xlo,
    const unsigned short* __restrict__ whiT, const unsigned short* __restrict__ wloT,
    float* __restrict__ q_t, float* __restrict__ k_t,
    float* __restrict__ v_t, float* __restrict__ g_t)
{
    __shared__ __align__(16) char smem[35840];  // GEMM: As|Bs|Cs ; pair: 8320B
    int bx = blockIdx.x;
    int t = threadIdx.x;
    int g3 = bx / 3, r3 = bx - g3 * 3;

    if (r3 != 2) {
        // ---------------- pair_bias ----------------
        float* As = (float*)smem;
        float* Spart = (float*)smem + 1552;
        float* Qpart = (float*)smem + 1816;
        int pair_id = g3 * 2 + r3;            // [0,1024)
        if (t < 128) {
            float lwc = lw[t];
#pragma unroll
            for (int h = 0; h < 8; h++)
                As[t * 12 + h] = lwc * wb[t * 8 + h] * LOG2E;
        }
        __syncthreads();
        {
            int h = t >> 5, seg = t & 31, cbase = seg * 4;
            float sa = 0, sq = 0;
#pragma unroll
            for (int cc = 0; cc < 4; cc++) {
                int c = cbase + cc;
                sa += As[c * 12 + h];
                sq += lb[c] * wb[c * 8 + h];
            }
            Spart[h * 33 + seg] = sa;
            Qpart[h * 33 + seg] = sq * LOG2E;
        }
        __syncthreads();
        if (t < 8) {
            float s = 0, q = 0;
#pragma unroll
            for (int j = 0; j < 32; j++) {
                s += Spart[t * 33 + j];
                q += Qpart[t * 33 + j];
            }
            As[1536 + t] = s;
            As[1544 + t] = q;
        }
        __syncthreads();
        int row = pair_id * 64 + (t >> 2);
        int q = t & 3;
        const float* in = pair + (size_t)row * PAIR_DIM;
        float4 x4[8];
#pragma unroll
        for (int it = 0; it < 8; it++)
            x4[it] = *(const float4*)&in[it * 16 + q * 4];
        float s = 0, s2 = 0;
        float dot[8] = {};
#pragma unroll
        for (int it = 0; it < 8; it++) {
            float xk[4];
            *(float4*)xk = x4[it];
#pragma unroll
            for (int k = 0; k < 4; k++) {
                int c = it * 16 + q * 4 + k;
                float xv = xk[k];
                s += xv; s2 += xv * xv;
                float4 A0 = *(const float4*)&As[c * 12];
                float4 A1 = *(const float4*)&As[c * 12 + 4];
                dot[0] += xv * A0.x; dot[1] += xv * A0.y;
                dot[2] += xv * A0.z; dot[3] += xv * A0.w;
                dot[4] += xv * A1.x; dot[5] += xv * A1.y;
                dot[6] += xv * A1.z; dot[7] += xv * A1.w;
            }
        }
        s = quad_sum(s);
        s2 = quad_sum(s2);
#pragma unroll
        for (int h = 0; h < 8; h++) dot[h] = quad_sum(dot[h]);
        float mu = s * (1.0f / 128.0f);
        float var = s2 * (1.0f / 128.0f) - mu * mu;
        float rs = rsqrtf(var + 1e-5f);
        int h0 = q * 2;
#pragma unroll
        for (int u = 0; u < 2; u++) {
            int h = h0 + u;
            b2[h * 65536 + row] = rs * (dot[h] - mu * As[1536 + h]) + As[1544 + h];
        }
    } else {
        // ---------------- xw GEMM, 64x64 tile ----------------
        unsigned short* As = (unsigned short*)smem;          // 64*72
        unsigned short* Bs = As + 64 * 72;                   // 64*72
        float* Cs = (float*)(smem + 18432);                  // 64*68
        int gid = g3;                                        // [0,512)
        int n0 = (gid & 15) * 64, m0 = (gid >> 4) * 64;
        int w = t >> 6, L = t & 63;
        int wm = (w & 1) * 32, wn = (w >> 1) * 32;
        int l15 = L & 15, l4 = L >> 4;
        int alm = t >> 3, alk = (t & 7) * 8;
        floatx4 acc[2][2];
#pragma unroll
        for (int a = 0; a < 2; a++)
#pragma unroll
            for (int b = 0; b < 2; b++) acc[a][b] = (floatx4){0, 0, 0, 0};

        short8 pa0 = *(const short8*)&xhi[(m0 + alm) * 256 + alk];
        short8 pa1 = *(const short8*)&xhi[(m0 + alm + 32) * 256 + alk];
        short8 pb[2];
#pragma unroll
        for (int j = 0; j < 2; j++) {
            int id = t + 256 * j;
            int bn = id >> 3, bc = (id & 7) * 8;
            pb[j] = *(const short8*)&whiT[(n0 + bn) * 256 + bc];
        }

        for (int r = 0; r < 12; r++) {
            __syncthreads();
            *(short8*)&As[alm * 72 + alk] = pa0;
            *(short8*)&As[(alm + 32) * 72 + alk] = pa1;
#pragma unroll
            for (int j = 0; j < 2; j++) {
                int id = t + 256 * j;
                int bn = id >> 3, bc = (id & 7) * 8;
                *(short8*)&Bs[bn * 72 + bc] = pb[j];
            }
            __syncthreads();
            if (r < 11) {
                int rn = r + 1;
                int seg = rn >> 2, kb = (rn & 3) * 64;
                const unsigned short* An = (seg == 1) ? xlo : xhi;
                const unsigned short* Bn = (seg == 2) ? wloT : whiT;
                pa0 = *(const short8*)&An[(m0 + alm) * 256 + kb + alk];
                pa1 = *(const short8*)&An[(m0 + alm + 32) * 256 + kb + alk];
#pragma unroll
                for (int j = 0; j < 2; j++) {
                    int id = t + 256 * j;
                    int bn = id >> 3, bc = (id & 7) * 8;
                    pb[j] = *(const short8*)&Bn[(n0 + bn) * 256 + kb + bc];
                }
            }
#pragma unroll
            for (int ks = 0; ks < 2; ks++) {
                int ko = ks * 32 + l4 * 8;
                short8 af[2], bf[2];
#pragma unroll
                for (int a = 0; a < 2; a++)
                    af[a] = *(short8*)&As[(wm + a * 16 + l15) * 72 + ko];
#pragma unroll
                for (int b = 0; b < 2; b++)
                    bf[b] = *(short8*)&Bs[(wn + b * 16 + l15) * 72 + ko];
#pragma unroll
                for (int a = 0; a < 2; a++)
#pragma unroll
                    for (int b = 0; b < 2; b++)
                        acc[a][b] = __builtin_amdgcn_mfma_f32_16x16x32_bf16(
                            af[a], bf[b], acc[a][b], 0, 0, 0);
            }
        }
#pragma unroll
        for (int a = 0; a < 2; a++)
#pragma unroll
            for (int b = 0; b < 2; b++) {
                int nl = wn + b * 16 + l15;
#pragma unroll
                for (int rg = 0; rg < 4; rg++) {
                    int ml = wm + a * 16 + l4 * 4 + rg;
                    Cs[ml * 68 + nl] = acc[a][b][rg];
                }
            }
        __syncthreads();
        int qkv_mode = (n0 < QKV_N);
        int chunk = n0 >> 8;
        int dbase = (n0 & 255) >> 3;
#pragma unroll
        for (int j = 0; j < 4; j++) {
            int id = t + 256 * j;             // [0,1024)
            int m = id >> 4;
            int h = (id >> 1) & 7;
            int dq = id & 1;
            float vals[4];
#pragma unroll
            for (int jj = 0; jj < 4; jj++)
                vals[jj] = Cs[m * 68 + (dq * 4 + jj) * 8 + h];
            int mm = m0 + m;
            int daddr = dbase + dq * 4;
            if (qkv_mode) {
                float* dst = (chunk == 0) ? q_t : ((chunk == 1) ? k_t : v_t);
                *(float4*)&dst[(size_t)(h * M_ROWS + mm) * D_DIM + daddr] =
                    *(float4*)vals;
            } else {
                float4 o;
                o.x = 1.0f / (1.0f + __expf(-vals[0]));
                o.y = 1.0f / (1.0f + __expf(-vals[1]));
                o.z = 1.0f / (1.0f + __expf(-vals[2]));
                o.w = 1.0f / (1.0f + __expf(-vals[3]));
                *(float4*)&g_t[(size_t)(h * M_ROWS + mm) * D_DIM + daddr] = o;
            }
        }
    }
}

// ---------------- Kernel 3: attention; emits ao as bf16 hi/lo --------------
// Block map: h = bx&7 (XCD-locality: all blocks of head h share an XCD via
// round-robin dispatch, so b2's 2MB head-slice stays L2-resident across the
// 8x s-reuse), s = (bx>>3)&7, it = bx>>6.
// LDS rows padded to stride 40 floats: bank group = (2*row+dg)%8 so every
// 8-lane phase of ds_read_b128 covers all 8 groups exactly once (the old
// stride-32 layout put all 4 j-rows of a wave on the same 4-bank group).
#define KV_STR 40
__global__ __launch_bounds__(256) void attn_kernel(
    const float* __restrict__ q_t, const float* __restrict__ k_t,
    const float* __restrict__ v_t, const float* __restrict__ g_t,
    const float* __restrict__ b2, unsigned short* __restrict__ ao_hi,
    unsigned short* __restrict__ ao_lo)
{
    __shared__ float k_sh[256 * KV_STR];
    __shared__ float v_sh[256 * KV_STR];
    int blk = blockIdx.x;
    int h = blk & 7, s = (blk >> 3) & 7, it = blk >> 6;
    int t = threadIdx.x;
    const float* kb = k_t + (size_t)(h * M_ROWS + s * N_RES) * D_DIM;
    const float* vb = v_t + (size_t)(h * M_ROWS + s * N_RES) * D_DIM;
    for (int idx = t; idx < 2048; idx += 256) {
        int row = idx >> 3, c = (idx & 7) << 2;
        *(float4*)&k_sh[row * KV_STR + c] = ((const float4*)kb)[idx];
        *(float4*)&v_sh[row * KV_STR + c] = ((const float4*)vb)[idx];
    }
    __syncthreads();
    int jp = t & 3, dg = (t >> 2) & 7, li = t >> 5;
    int d0 = dg * 4;
    const float SCL2 = 0.17677669529663687f * LOG2E;
    int ig[4], mrow[4];
    float qs[4][4];
#pragma unroll
    for (int r = 0; r < 4; r++) {
        ig[r] = it * 32 + r * 8 + li;
        mrow[r] = s * N_RES + ig[r];
        float4 q4 = *(const float4*)&q_t[(size_t)(h * M_ROWS + mrow[r]) * D_DIM + d0];
        qs[r][0] = q4.x * SCL2; qs[r][1] = q4.y * SCL2;
        qs[r][2] = q4.z * SCL2; qs[r][3] = q4.w * SCL2;
    }
    float den[4][4] = {}, acc[4][4] = {};
    const float* bbase = b2 + h * 65536;
    for (int js4 = 0; js4 < 16; js4++) {
        float bb[4][4];
#pragma unroll
        for (int r = 0; r < 4; r++)
            *(float4*)&bb[r][0] =
                *(const float4*)&bbase[ig[r] * 256 + jp * 64 + js4 * 4];
#pragma unroll
        for (int u = 0; u < 4; u++) {
            int j = jp * 64 + js4 * 4 + u;
            float ka[4], va[4];
            *(float4*)ka = *(const float4*)&k_sh[j * KV_STR + d0];
            *(float4*)va = *(const float4*)&v_sh[j * KV_STR + d0];
#pragma unroll
            for (int r = 0; r < 4; r++) {
#pragma unroll
                for (int c = 0; c < 4; c++) {
                    float e = __builtin_amdgcn_exp2f(qs[r][c] * ka[c] + bb[r][u]);
                    den[r][c] += e;
                    acc[r][c] += e * va[c];
                }
            }
        }
    }
#pragma unroll
    for (int r = 0; r < 4; r++)
#pragma unroll
        for (int c = 0; c < 4; c++) {
            den[r][c] = quad_sum(den[r][c]);
            acc[r][c] = quad_sum(acc[r][c]);
        }
    if (jp == 0) {
#pragma unroll
        for (int r = 0; r < 4; r++) {
            float4 g4 = *(const float4*)&g_t[(size_t)(h * M_ROWS + mrow[r]) * D_DIM + d0];
            float o[4];
            o[0] = g4.x * acc[r][0] / den[r][0];
            o[1] = g4.y * acc[r][1] / den[r][1];
            o[2] = g4.z * acc[r][2] / den[r][2];
            o[3] = g4.w * acc[r][3] / den[r][3];
            unsigned short hi[4], lo[4];
#pragma unroll
            for (int c = 0; c < 4; c++) {
                hi[c] = bf16rn(o[c]);
                lo[c] = bf16rn(o[c] - __uint_as_float((unsigned)hi[c] << 16));
            }
            size_t base = (size_t)mrow[r] * 256 + h * 32 + d0;
            uint2 ph, pl;
            ph.x = (unsigned)hi[0] | ((unsigned)hi[1] << 16);
            ph.y = (unsigned)hi[2] | ((unsigned)hi[3] << 16);
            pl.x = (unsigned)lo[0] | ((unsigned)lo[1] << 16);
            pl.y = (unsigned)lo[2] | ((unsigned)lo[3] << 16);
            *(uint2*)&ao_hi[base] = ph;
            *(uint2*)&ao_lo[base] = pl;
        }
    }
}

// ------- Kernel 4: out projection via bf16x3 MFMA + bias -------------------
// Retiled 32x64 -> grid (4,64) = 256 blocks (was 64 blocks = 75% CUs idle).
__global__ __launch_bounds__(256) void out_mfma_kernel(
    const unsigned short* __restrict__ ahi, const unsigned short* __restrict__ alo,
    const unsigned short* __restrict__ whi, const unsigned short* __restrict__ wlo,
    const float* __restrict__ bias, float* __restrict__ out)
{
    __shared__ unsigned short As[32 * 72];
    __shared__ unsigned short Bs[64 * 72];
    __shared__ float Cs[32 * 68];
    int t = threadIdx.x;
    int n0 = blockIdx.x * 64, m0 = blockIdx.y * 32;
    int w = t >> 6, L = t & 63;
    int wm = (w & 1) * 16, wn = (w >> 1) * 32;
    int l15 = L & 15, l4 = L >> 4;
    int alm = t >> 3, alk = (t & 7) * 8;
    floatx4 acc[2];
#pragma unroll
    for (int b = 0; b < 2; b++) acc[b] = (floatx4){0, 0, 0, 0};

    short8 pa0 = *(const short8*)&ahi[(m0 + alm) * 256 + alk];
    short8 pb[2];
#pragma unroll
    for (int j = 0; j < 2; j++) {
        int id = t + 256 * j;
        int bn = id >> 3, bc = (id & 7) * 8;
        pb[j] = *(const short8*)&whi[(n0 + bn) * 256 + bc];
    }

    for (int r = 0; r < 12; r++) {
        __syncthreads();
        *(short8*)&As[alm * 72 + alk] = pa0;
#pragma unroll
        for (int j = 0; j < 2; j++) {
            int id = t + 256 * j;
            int bn = id >> 3, bc = (id & 7) * 8;
            *(short8*)&Bs[bn * 72 + bc] = pb[j];
        }
        __syncthreads();
        if (r < 11) {
            int rn = r + 1;
            int seg = rn >> 2, kb = (rn & 3) * 64;
            const unsigned short* An = (seg == 1) ? alo : ahi;
            const unsigned short* Bn = (seg == 2) ? wlo : whi;
            pa0 = *(const short8*)&An[(m0 + alm) * 256 + kb + alk];
#pragma unroll
            for (int j = 0; j < 2; j++) {
                int id = t + 256 * j;
                int bn = id >> 3, bc = (id & 7) * 8;
                pb[j] = *(const short8*)&Bn[(n0 + bn) * 256 + kb + bc];
            }
        }
#pragma unroll
        for (int ks = 0; ks < 2; ks++) {
            int ko = ks * 32 + l4 * 8;
            short8 af, bf[2];
            af = *(short8*)&As[(wm + l15) * 72 + ko];
#pragma unroll
            for (int b = 0; b < 2; b++)
                bf[b] = *(short8*)&Bs[(wn + b * 16 + l15) * 72 + ko];
#pragma unroll
            for (int b = 0; b < 2; b++)
                acc[b] = __builtin_amdgcn_mfma_f32_16x16x32_bf16(
                    af, bf[b], acc[b], 0, 0, 0);
        }
    }
#pragma unroll
    for (int b = 0; b < 2; b++) {
        int nl = wn + b * 16 + l15;
#pragma unroll
        for (int rg = 0; rg < 4; rg++) {
            int ml = wm + l4 * 4 + rg;
            Cs[ml * 68 + nl] = acc[b][rg];
        }
    }
    __syncthreads();
#pragma unroll
    for (int j = 0; j < 2; j++) {
        int id = t + 256 * j;                 // [0,512)
        int m = id >> 4, nc = (id & 15) * 4;
        float4 v = *(float4*)&Cs[m * 68 + nc];
        float4 bb = *(const float4*)&bias[n0 + nc];
        float4 o;
        o.x = v.x + bb.x; o.y = v.y + bb.y;
        o.z = v.z + bb.z; o.w = v.w + bb.w;
        *(float4*)&out[(size_t)(m0 + m) * 256 + n0 + nc] = o;
    }
}

extern "C" void kernel_launch(void* const* d_in, const int* in_sizes, int n_in,
                              void* d_out, int out_size, void* d_ws, size_t ws_size,
                              hipStream_t stream)
{
    const float* msa_rep   = (const float*)d_in[0];
    const float* pair_rep  = (const float*)d_in[1];
    const float* ln_w      = (const float*)d_in[2];
    const float* ln_b      = (const float*)d_in[3];
    const float* w_qkv     = (const float*)d_in[4];
    const float* ln_pair_w = (const float*)d_in[5];
    const float* ln_pair_b = (const float*)d_in[6];
    const float* w_b       = (const float*)d_in[7];
    const float* w_g       = (const float*)d_in[8];
    const float* w_out     = (const float*)d_in[9];
    const float* b_out     = (const float*)d_in[10];
    float* out = (float*)d_out;

    float* ws = (float*)d_ws;
    const size_t CH = 524288;     // 2048*256 floats
    float* q_t = ws + 0 * CH;
    float* k_t = ws + 1 * CH;
    float* v_t = ws + 2 * CH;
    float* g_t = ws + 3 * CH;
    float* b2  = ws + 4 * CH;
    unsigned short* ao_hi   = (unsigned short*)(ws + 5 * CH);
    unsigned short* ao_lo   = ao_hi + (size_t)M_ROWS * 256;
    unsigned short* xhi     = (unsigned short*)(ws + 6 * CH);
    unsigned short* xlo     = xhi + (size_t)M_ROWS * 256;
    unsigned short* whiT    = (unsigned short*)(ws + 7 * CH);
    unsigned short* wloT    = whiT + (size_t)XW_N * 256;
    unsigned short* wouthiT = (unsigned short*)(ws + 8 * CH);
    unsigned short* woutloT = wouthiT + 65536;

    prep_kernel<<<2208, 256, 0, stream>>>(
        w_qkv, w_g, whiT, wloT,
        w_out, wouthiT, woutloT,
        msa_rep, ln_w, ln_b, xhi, xlo);

    mid_kernel<<<1536, 256, 0, stream>>>(
        pair_rep, ln_pair_w, ln_pair_b, w_b, b2,
        xhi, xlo, whiT, wloT, q_t, k_t, v_t, g_t);

    attn_kernel<<<512, 256, 0, stream>>>(q_t, k_t, v_t, g_t, b2, ao_hi, ao_lo);

    out_mfma_kernel<<<dim3(4, 64), 256, 0, stream>>>(
        ao_hi, ao_lo, wouthiT, woutloT, b_out, out);
}